// Round 1
// baseline (37.663 us; speedup 1.0000x reference)
//
#include <hip/hip_runtime.h>

// SpecAugment: time-warp (shift gather, W=80) + freq mask + time mask.
// B=128, M=80, T=3000 fp32. Memory-bound: ~246 MB traffic -> ~39us floor.

#define Bn 128
#define Mn 80
#define Tn 3000
#define Wn 80
#define TV (Tn / 4)  // 750 float4 per row; W%4==0 keeps shifted loads aligned

__global__ __launch_bounds__(256) void specaug_kernel(
    const float* __restrict__ spec,
    const int*   __restrict__ centers,
    const int*   __restrict__ p_fs, const int* __restrict__ p_fw,
    const int*   __restrict__ p_ts, const int* __restrict__ p_tw,
    float*       __restrict__ out)
{
    const int bm = blockIdx.x;            // one block per (b,m) row
    const int b  = bm / Mn;
    const int m  = bm - b * Mn;

    const int fs = *p_fs, fw = *p_fw, ts = *p_ts, tw = *p_tw;
    const int c  = centers[b];            // warp center for this sample

    const float* row  = spec + (size_t)bm * Tn;
    float*       orow = out  + (size_t)bm * Tn;

    const bool fmasked = (m >= fs) && (m < fs + fw);

    for (int v = threadIdx.x; v < TV; v += 256) {
        const int t4 = v * 4;
        float r[4];

        if (fmasked) {
            r[0] = r[1] = r[2] = r[3] = 0.f;
        } else if (t4 + 3 < c) {
            // left region: idx = t - W. All-valid iff t4 >= W (alignment makes
            // partial vectors impossible: W%4==0).
            if (t4 >= Wn) {
                float4 v4 = *reinterpret_cast<const float4*>(row + (t4 - Wn));
                r[0] = v4.x; r[1] = v4.y; r[2] = v4.z; r[3] = v4.w;
            } else {
                r[0] = r[1] = r[2] = r[3] = 0.f;
            }
        } else if (t4 >= c) {
            // right region: idx = t + W. All-valid iff t4+3+W <= T-1.
            if (t4 <= Tn - Wn - 4) {
                float4 v4 = *reinterpret_cast<const float4*>(row + (t4 + Wn));
                r[0] = v4.x; r[1] = v4.y; r[2] = v4.z; r[3] = v4.w;
            } else {
                r[0] = r[1] = r[2] = r[3] = 0.f;
            }
        } else {
            // the single vector straddling c: scalar gather with bounds check
            #pragma unroll
            for (int j = 0; j < 4; ++j) {
                const int t   = t4 + j;
                const int idx = (t < c) ? (t - Wn) : (t + Wn);
                r[j] = (idx >= 0 && idx < Tn) ? row[idx] : 0.f;
            }
        }

        if (!fmasked) {
            #pragma unroll
            for (int j = 0; j < 4; ++j) {
                const int t = t4 + j;
                if (t >= ts && t < ts + tw) r[j] = 0.f;
            }
        }

        *reinterpret_cast<float4*>(orow + t4) = *reinterpret_cast<float4*>(r);
    }
}

extern "C" void kernel_launch(void* const* d_in, const int* in_sizes, int n_in,
                              void* d_out, int out_size, void* d_ws, size_t ws_size,
                              hipStream_t stream) {
    const float* spec    = (const float*)d_in[0];
    const int*   centers = (const int*)d_in[1];
    const int*   p_fs    = (const int*)d_in[2];
    const int*   p_fw    = (const int*)d_in[3];
    const int*   p_ts    = (const int*)d_in[4];
    const int*   p_tw    = (const int*)d_in[5];
    float*       out     = (float*)d_out;

    specaug_kernel<<<dim3(Bn * Mn), dim3(256), 0, stream>>>(
        spec, centers, p_fs, p_fw, p_ts, p_tw, out);
}